// Round 6
// baseline (292.028 us; speedup 1.0000x reference)
//
#include <hip/hip_runtime.h>

// ---------------------------------------------------------------------------
// ANHPMultiHeadAttention: fused QKV projection + exp-scored causal attention
// B=8, S=1024, FEAT=HID=1024, H=8, DH=128.
//
// R6 changes vs R5 (evidence: attn is latency-bound -> maximize waves/CU;
// gemm K-loop is LDS-read-bound: 16 b128 reads ~192cyc > 32 MFMA ~155cyc):
//  - GEMM: B-fragments read DIRECTLY from global (W^T is 2MB/matrix,
//    L2/L3-resident, re-read by 64 m-blocks). Bs eliminated -> LDS reads
//    halve (96cyc < MFMA 155cyc), LDS 64->32KB -> 4 blocks/CU = 16 waves/CU.
//    B-loads issued BEFORE the A-prefetch so their vmcnt wait (FIFO) does
//    not drain the in-flight A stage.
//  - ATTN: R4's occupancy shape (BQ=64: 16 q-rows/wave, ~100 VGPR) +
//    V-fragments DIRECT from global (V^T rows match the O^T A-frag layout;
//    4 waves/block share the same 8KB slice -> L1). Ks dbuf BK=64 (256B
//    rows, conflict-free), Ps 4KB -> 36KB LDS, 4 blocks/CU = 16 waves/CU.
// ---------------------------------------------------------------------------

typedef __bf16 bf16x8 __attribute__((ext_vector_type(8)));
typedef float floatx4 __attribute__((ext_vector_type(4)));
typedef unsigned short u16;
typedef unsigned int u32;

#define RSCALE 0.08838834764831845f   // 1/sqrt(128)

__device__ __forceinline__ u16 f2b(float f) {       // fp32 -> bf16 bits, RNE
  union { float f; unsigned u; } v; v.f = f;
  return (u16)((v.u + 0x7FFFu + ((v.u >> 16) & 1u)) >> 16);
}

// async global->LDS, 16B per lane. LDS dst = wave-uniform base + lane*16.
__device__ __forceinline__ void gld_lds16(const void* g, void* l) {
  __builtin_amdgcn_global_load_lds(
      (const __attribute__((address_space(1))) unsigned*)g,
      (__attribute__((address_space(3))) unsigned*)l, 16, 0, 0);
}

#define MFMA16(a, b, c) __builtin_amdgcn_mfma_f32_16x16x32_bf16(a, b, c, 0, 0, 0)

// ---------------------------------------------------------------------------
// Kernel 1: prep = cast X (blocks 0..8191) + transpose W (blocks 8192..11263)
// ---------------------------------------------------------------------------
__global__ __launch_bounds__(256) void prep_kernel(
    const float4* __restrict__ X, u16* __restrict__ Xb,
    const float* __restrict__ Wq, const float* __restrict__ Wk,
    const float* __restrict__ Wv, u16* __restrict__ Wtb) {
  if (blockIdx.x < 8192) {
    unsigned i = blockIdx.x * 256u + threadIdx.x;
    float4 v = X[i];
    ushort4 o;
    o.x = f2b(v.x); o.y = f2b(v.y); o.z = f2b(v.z); o.w = f2b(v.w);
    *reinterpret_cast<ushort4*>(Xb + 4u * i) = o;
  } else {
    const int bid = blockIdx.x - 8192;          // 0..3071
    const int mat = bid >> 10;                  // 1024 blocks per matrix
    const int bx = bid & 31, by = (bid >> 5) & 31;
    const float* W = (mat == 0) ? Wq : (mat == 1) ? Wk : Wv;
    u16* Wt = Wtb + (size_t)mat * (1024u * 1024u);
    __shared__ u16 tile[32][33];
    const int x = threadIdx.x & 31, y = threadIdx.x >> 5;
    const int kt = bx * 32, nt = by * 32;
#pragma unroll
    for (int i = 0; i < 4; ++i)
      tile[y + 8 * i][x] = f2b(W[(size_t)(kt + y + 8 * i) * 1024 + nt + x]);
    __syncthreads();
#pragma unroll
    for (int i = 0; i < 4; ++i)
      Wt[(size_t)(nt + y + 8 * i) * 1024 + kt + x] = tile[x][y + 8 * i];
  }
}

// ---------------------------------------------------------------------------
// Kernel 2: QKV GEMM. 128x128 tile, BK=64. A staged in LDS (dbuf, 128B rows,
// xor8, conflict-free); B-frags direct from global (W^T rows, L2-resident).
// 32KB LDS -> 4 blocks/CU = 16 waves/CU. grid (64,8,3).
// Q,K stored [B,H,S,DH]; V stored [B,H,DH,S] (transposed).
// ---------------------------------------------------------------------------
__global__ __launch_bounds__(256, 4) void gemm_qkv_kernel(
    const u16* __restrict__ Xb, const u16* __restrict__ Wtb,
    const float* __restrict__ bq, const float* __restrict__ bk,
    const float* __restrict__ bv, u16* __restrict__ Qh, u16* __restrict__ Kh,
    u16* __restrict__ Vt) {
  const int mat = blockIdx.z;
  const u16* __restrict__ Wt = Wtb + (size_t)mat * (1024u * 1024u);
  const float* __restrict__ bias = (mat == 0) ? bq : (mat == 1) ? bk : bv;

  const int m0 = blockIdx.x * 128;
  const int n0 = blockIdx.y * 128;

  __shared__ u16 As[2][128 * 64];   // [m][k] 16KB per buf, 128B rows

  const int tid = threadIdx.x;
  const int wid = tid >> 6;
  const int lane = tid & 63;
  const int quad = lane >> 4;
  const int l16 = lane & 15;
  const int wm = (wid & 1) * 64;
  const int wn = (wid >> 1) * 64;

  const floatx4 z4 = {0.f, 0.f, 0.f, 0.f};
  floatx4 acc[4][4];
#pragma unroll
  for (int i = 0; i < 4; ++i)
#pragma unroll
    for (int j = 0; j < 4; ++j) acc[i][j] = z4;

  // A staging: wave loads 32 rows, 8 rows (1KB) per call, xor8 swizzle.
  const int srow = wid * 32;
  const int lrow = lane >> 3;
  const int gblk = (lane & 7) ^ lrow;

  auto stageA = [&](int b, int k0) {
#pragma unroll
    for (int c = 0; c < 4; ++c) {
      const int row = srow + c * 8 + lrow;
      gld_lds16(Xb + (size_t)(m0 + row) * 1024 + k0 + gblk * 8,
                As[b] + (srow + c * 8) * 64);
    }
  };

  // B rows (W^T): lane l16 -> row n0+wn+j*16+l16, k-chunk quad*8 (+c*32).
  const u16* Brow[4];
#pragma unroll
  for (int j = 0; j < 4; ++j)
    Brow[j] = Wt + (size_t)(n0 + wn + j * 16 + l16) * 1024 + quad * 8;

  stageA(0, 0);

  for (int i = 0; i < 16; ++i) {
    __syncthreads();                 // drains A prefetch(i)
    const int k0 = i * 64;
    // B loads FIRST (older in vmcnt FIFO than the A stage below, so the
    // compiler's wait before their use leaves the A prefetch in flight).
    bf16x8 b0[4], b1[4];
#pragma unroll
    for (int j = 0; j < 4; ++j) b0[j] = *(const bf16x8*)(Brow[j] + k0);
#pragma unroll
    for (int j = 0; j < 4; ++j) b1[j] = *(const bf16x8*)(Brow[j] + k0 + 32);
    if (i < 15) stageA((i + 1) & 1, k0 + 64);

    const u16* __restrict__ Ab = As[i & 1];
#pragma unroll
    for (int c = 0; c < 2; ++c) {
      const int phys = ((c * 4 + quad) ^ (l16 & 7)) * 8;
      bf16x8 af[4];
#pragma unroll
      for (int ii = 0; ii < 4; ++ii)
        af[ii] = *(const bf16x8*)(Ab + (wm + ii * 16 + l16) * 64 + phys);
#pragma unroll
      for (int ii = 0; ii < 4; ++ii)
#pragma unroll
        for (int j = 0; j < 4; ++j)
          acc[ii][j] = MFMA16(af[ii], c ? b1[j] : b0[j], acc[ii][j]);
    }
  }

  // epilogue (R2-proven). C/D layout: col = l16 (n), row = quad*4 + reg (m).
  const int b = m0 >> 10;
  const int h = n0 >> 7;
  const int sbase = (m0 & 1023) + wm;
  float bv4[4];
#pragma unroll
  for (int j = 0; j < 4; ++j) bv4[j] = bias[n0 + wn + j * 16 + l16];

  if (mat < 2) {
    u16* outp = (mat == 0 ? Qh : Kh) + (size_t)(b * 8 + h) * 1024 * 128;
#pragma unroll
    for (int i = 0; i < 4; ++i)
#pragma unroll
      for (int j = 0; j < 4; ++j) {
        const int d = wn + j * 16 + l16;
#pragma unroll
        for (int r = 0; r < 4; ++r) {
          const int s = sbase + i * 16 + quad * 4 + r;
          outp[(size_t)s * 128 + d] = f2b(acc[i][j][r] + bv4[j]);
        }
      }
  } else {
    // V^T: out[((b*8+h)*128 + d)*1024 + s]; 4 regs = 4 consecutive s.
    u16* outp = Vt + (size_t)(b * 8 + h) * 128 * 1024;
#pragma unroll
    for (int i = 0; i < 4; ++i)
#pragma unroll
      for (int j = 0; j < 4; ++j) {
        const int d = wn + j * 16 + l16;
        const int s = sbase + i * 16 + quad * 4;
        ushort4 pk;
        pk.x = f2b(acc[i][j][0] + bv4[j]);
        pk.y = f2b(acc[i][j][1] + bv4[j]);
        pk.z = f2b(acc[i][j][2] + bv4[j]);
        pk.w = f2b(acc[i][j][3] + bv4[j]);
        *(ushort4*)(outp + (size_t)d * 1024 + s) = pk;
      }
  }
}

// ---------------------------------------------------------------------------
// Kernel 3: attention. grid 1024 (64 bh x 16 qtiles of 64), block 256
// (4 waves, each owns 16 q-rows). BK=64, Ks double-buffered (single barrier
// per iter), V-frags DIRECT from global (V^T row = O^T A-frag layout; the 4
// waves share an 8KB V slice -> L1). 36KB LDS -> 4 blocks/CU = 16 waves/CU.
// S^T = MFMA(kf,qf) -> packed uint2 P-writes; O^T = MFMA(vf,pa) -> float4
// stores. Per-half causal skip; LPT + XCD swizzle.
// ---------------------------------------------------------------------------
__global__ __launch_bounds__(256, 4) void attn_kernel(const u16* __restrict__ Qh,
                                                      const u16* __restrict__ Kh,
                                                      const u16* __restrict__ Vt,
                                                      float* __restrict__ out) {
  const int id = blockIdx.x;
  const int bh = (id & 7) * 8 + ((id >> 3) & 7);   // XCD x owns 8 heads
  const int qt = 15 - (id >> 6);                   // heavy tiles first (LPT)
  const int q0 = qt * 64;

  const int tid = threadIdx.x;
  const int wid = tid >> 6;
  const int lane = tid & 63;
  const int quad = lane >> 4;
  const int l16 = lane & 15;

  __shared__ u16 Ks[2][64 * 128];   // [key][d] 256B rows, xor16 units, 16KB ea
  __shared__ u16 Ps[4][16 * 32];    // per-wave [q][32-key half] 64B rows, 1KB

  const u16* __restrict__ Qbase = Qh + (size_t)bh * 1024 * 128;
  const u16* __restrict__ Kbase = Kh + (size_t)bh * 1024 * 128;
  const u16* __restrict__ Vbase = Vt + (size_t)bh * 128 * 1024;

  const int qw = q0 + wid * 16;     // this wave's 16 q-rows
  const int qrow = qw + l16;

  // Q B-frags (for S^T = MFMA(kf,qf)): lane l16 = q, k = quad*8+j.
  bf16x8 qf[4];
#pragma unroll
  for (int c = 0; c < 4; ++c)
    qf[c] = *(const bf16x8*)(Qbase + (size_t)qrow * 128 + c * 32 + quad * 8);

  const floatx4 z4 = {0.f, 0.f, 0.f, 0.f};
  floatx4 o[8];
#pragma unroll
  for (int dt = 0; dt < 8; ++dt) o[dt] = z4;
  float lacc = 0.f;

  // K staging: tile 64 keys x 256B; wave stages 16 rows, 4 rows (1KB)/call.
  auto stageK = [&](int b, int k0) {
#pragma unroll
    for (int c = 0; c < 4; ++c) {
      const int r0 = wid * 16 + c * 4;
      const int row = r0 + quad;                      // row & 15 = c*4+quad
      gld_lds16(Kbase + (size_t)(k0 + row) * 128 + ((l16 ^ (c * 4 + quad)) * 8),
                Ks[b] + r0 * 128);
    }
  };

  const int n = qt + 1;             // 64-key iterations
  stageK(0, 0);
  const int s4 = l16 & 3;

  for (int i = 0; i < n; ++i) {
    const int k0 = i << 6;
    __syncthreads();                // drains K prefetch(i); frees buf (i-1)&1
    if (i + 1 < n) stageK((i + 1) & 1, k0 + 64);

    const u16* __restrict__ Kb = Ks[i & 1];

#pragma unroll
    for (int half = 0; half < 2; ++half) {
      if (k0 + half * 32 > qw + 15) break;   // wave-uniform causal skip

      // QK: two 16-key S^T tiles; pack P into Ps.
#pragma unroll
      for (int f2 = 0; f2 < 2; ++f2) {
        const int f = half * 2 + f2;
        bf16x8 kf[4];
#pragma unroll
        for (int c = 0; c < 4; ++c)
          kf[c] = *(const bf16x8*)(Kb + (f * 16 + l16) * 128 +
                                   (((c * 4 + quad) ^ l16) * 8));
        floatx4 st = z4;
#pragma unroll
        for (int c = 0; c < 4; ++c) st = MFMA16(kf[c], qf[c], st);
        const int kb = k0 + f * 16 + quad * 4;
        float p[4];
#pragma unroll
        for (int r = 0; r < 4; ++r) {
          const float e = fminf(__expf(st[r] * RSCALE), 85.f);
          p[r] = (kb + r > qrow) ? 0.f : __expf(e);
        }
        lacc += (p[0] + p[1]) + (p[2] + p[3]);
        uint2 pk;
        pk.x = (u32)f2b(p[0]) | ((u32)f2b(p[1]) << 16);
        pk.y = (u32)f2b(p[2]) | ((u32)f2b(p[3]) << 16);
        *(uint2*)((char*)Ps[wid] + l16 * 64 +
                  (((f2 * 2 + (quad >> 1)) ^ s4) * 16) + (quad & 1) * 8) = pk;
      }
      asm volatile("s_waitcnt lgkmcnt(0)" ::: "memory");  // own P visible

      // PV: pa from Ps; vf DIRECT from global V^T (A[m=d][k=key] layout).
      const bf16x8 pa = *(const bf16x8*)((char*)Ps[wid] + l16 * 64 +
                                         ((quad ^ s4) * 16));
      const size_t voff = (size_t)k0 + half * 32 + quad * 8;
#pragma unroll
      for (int dt = 0; dt < 8; ++dt) {
        const bf16x8 vf =
            *(const bf16x8*)(Vbase + (size_t)(dt * 16 + l16) * 1024 + voff);
        o[dt] = MFMA16(vf, pa, o[dt]);
      }
    }
  }

  // l reduce across quads (lanes sharing l16), normalize, store.
  float s = lacc;
  s += __shfl_xor(s, 16);
  s += __shfl_xor(s, 32);
  const float linv = 1.0f / s;

  // O^T C-layout: col(l16)=q, row(quad*4+r)=d -> contiguous float4.
  float* outp = out + (size_t)(bh >> 3) * 1024 * 1024 + (bh & 7) * 128;
#pragma unroll
  for (int dt = 0; dt < 8; ++dt) {
    float4 v;
    v.x = o[dt][0] * linv;
    v.y = o[dt][1] * linv;
    v.z = o[dt][2] * linv;
    v.w = o[dt][3] * linv;
    *(float4*)(outp + (size_t)qrow * 1024 + dt * 16 + quad * 4) = v;
  }
}

// ---------------------------------------------------------------------------
extern "C" void kernel_launch(void* const* d_in, const int* in_sizes, int n_in,
                              void* d_out, int out_size, void* d_ws,
                              size_t ws_size, hipStream_t stream) {
  const float* X = (const float*)d_in[0];
  const float* Wq = (const float*)d_in[1];
  const float* bq = (const float*)d_in[2];
  const float* Wk = (const float*)d_in[3];
  const float* bk = (const float*)d_in[4];
  const float* Wv = (const float*)d_in[5];
  const float* bv = (const float*)d_in[6];
  float* out = (float*)d_out;

  char* ws = (char*)d_ws;
  u16* Xb  = (u16*)(ws);                         // 16 MB  bf16 X
  u16* Wtb = (u16*)(ws + (16u << 20));           //  6 MB  bf16 W^T x3
  u16* Qh  = (u16*)(ws + (22u << 20));           // 16 MB  [B,H,S,DH]
  u16* Kh  = (u16*)(ws + (38u << 20));           // 16 MB  [B,H,S,DH]
  u16* Vt  = (u16*)(ws + (54u << 20));           // 16 MB  [B,H,DH,S]

  prep_kernel<<<8192 + 3072, 256, 0, stream>>>((const float4*)X, Xb, Wq, Wk,
                                               Wv, Wtb);
  dim3 gg(64, 8, 3);
  gemm_qkv_kernel<<<gg, 256, 0, stream>>>(Xb, Wtb, bq, bk, bv, Qh, Kh, Vt);
  attn_kernel<<<1024, 256, 0, stream>>>(Qh, Kh, Vt, out);
}

// Round 7
// 201.523 us; speedup vs baseline: 1.4491x; 1.4491x over previous
//
#include <hip/hip_runtime.h>

// ---------------------------------------------------------------------------
// ANHPMultiHeadAttention: fused QKV projection + exp-scored causal attention
// B=8, S=1024, FEAT=HID=1024, H=8, DH=128.
//
// R7 changes vs R6 (R6's direct-from-global operands were latency-exposed and
// regressed badly -> all MFMA operands come from LDS via prefetched
// global_load_lds again):
//  - GEMM: the untested matrix cell: BK=32 double-buffered (32KB LDS -> 4
//    blocks/CU = 16 waves/CU) AND conflict-free, via PAIR-INTERLEAVED rows:
//    phys LDS row r (128B) holds m-rows {2r, 2r+1} (64B each), 16B units
//    xor-swizzled by (r&3). Bank math: af/bf b128 reads are uniform
//    8 words/bank (the size floor).
//  - ATTN: R4's best-known shape (36KB, 4 blocks/CU, BK=32, Ks+Vs dbuf,
//    single barrier) but with the 8-way-conflicted Vs/Ps reads fixed by the
//    same pair-interleave (Vs: d-pairs per 128B row; Ps: q-pairs per 128B
//    row). kf path (verified free) unchanged.
// ---------------------------------------------------------------------------

typedef __bf16 bf16x8 __attribute__((ext_vector_type(8)));
typedef float floatx4 __attribute__((ext_vector_type(4)));
typedef unsigned short u16;
typedef unsigned int u32;

#define RSCALE 0.08838834764831845f   // 1/sqrt(128)

__device__ __forceinline__ u16 f2b(float f) {       // fp32 -> bf16 bits, RNE
  union { float f; unsigned u; } v; v.f = f;
  return (u16)((v.u + 0x7FFFu + ((v.u >> 16) & 1u)) >> 16);
}

// async global->LDS, 16B per lane. LDS dst = wave-uniform base + lane*16.
__device__ __forceinline__ void gld_lds16(const void* g, void* l) {
  __builtin_amdgcn_global_load_lds(
      (const __attribute__((address_space(1))) unsigned*)g,
      (__attribute__((address_space(3))) unsigned*)l, 16, 0, 0);
}

#define MFMA16(a, b, c) __builtin_amdgcn_mfma_f32_16x16x32_bf16(a, b, c, 0, 0, 0)

// ---------------------------------------------------------------------------
// Kernel 1: prep = cast X (blocks 0..8191) + transpose W (blocks 8192..11263)
// ---------------------------------------------------------------------------
__global__ __launch_bounds__(256) void prep_kernel(
    const float4* __restrict__ X, u16* __restrict__ Xb,
    const float* __restrict__ Wq, const float* __restrict__ Wk,
    const float* __restrict__ Wv, u16* __restrict__ Wtb) {
  if (blockIdx.x < 8192) {
    unsigned i = blockIdx.x * 256u + threadIdx.x;
    float4 v = X[i];
    ushort4 o;
    o.x = f2b(v.x); o.y = f2b(v.y); o.z = f2b(v.z); o.w = f2b(v.w);
    *reinterpret_cast<ushort4*>(Xb + 4u * i) = o;
  } else {
    const int bid = blockIdx.x - 8192;          // 0..3071
    const int mat = bid >> 10;                  // 1024 blocks per matrix
    const int bx = bid & 31, by = (bid >> 5) & 31;
    const float* W = (mat == 0) ? Wq : (mat == 1) ? Wk : Wv;
    u16* Wt = Wtb + (size_t)mat * (1024u * 1024u);
    __shared__ u16 tile[32][33];
    const int x = threadIdx.x & 31, y = threadIdx.x >> 5;
    const int kt = bx * 32, nt = by * 32;
#pragma unroll
    for (int i = 0; i < 4; ++i)
      tile[y + 8 * i][x] = f2b(W[(size_t)(kt + y + 8 * i) * 1024 + nt + x]);
    __syncthreads();
#pragma unroll
    for (int i = 0; i < 4; ++i)
      Wt[(size_t)(nt + y + 8 * i) * 1024 + kt + x] = tile[x][y + 8 * i];
  }
}

// ---------------------------------------------------------------------------
// Kernel 2: QKV GEMM. 128x128 tile, BK=32, pair-interleaved 128B LDS rows
// (conflict-free), double-buffered single-barrier pipeline, 32KB LDS ->
// 4 blocks/CU. grid (64,8,3). Q,K stored [B,H,S,DH]; V [B,H,DH,S].
// LDS layout: phys row r (64 u16) = {m=2r (units 0..3), m=2r+1 (units 4..7)},
// 16B unit j stored at phys (j ^ (r&3)) within its half.
// ---------------------------------------------------------------------------
__global__ __launch_bounds__(256, 4) void gemm_qkv_kernel(
    const u16* __restrict__ Xb, const u16* __restrict__ Wtb,
    const float* __restrict__ bq, const float* __restrict__ bk,
    const float* __restrict__ bv, u16* __restrict__ Qh, u16* __restrict__ Kh,
    u16* __restrict__ Vt) {
  const int mat = blockIdx.z;
  const u16* __restrict__ Wt = Wtb + (size_t)mat * (1024u * 1024u);
  const float* __restrict__ bias = (mat == 0) ? bq : (mat == 1) ? bk : bv;

  const int m0 = blockIdx.x * 128;
  const int n0 = blockIdx.y * 128;

  __shared__ u16 As[2][64 * 64];    // 64 phys rows x 128B = 8KB per buf
  __shared__ u16 Bs[2][64 * 64];

  const int tid = threadIdx.x;
  const int wid = tid >> 6;
  const int lane = tid & 63;
  const int quad = lane >> 4;
  const int l16 = lane & 15;
  const int wm = (wid & 1) * 64;
  const int wn = (wid >> 1) * 64;

  const floatx4 z4 = {0.f, 0.f, 0.f, 0.f};
  floatx4 acc[4][4];
#pragma unroll
  for (int i = 0; i < 4; ++i)
#pragma unroll
    for (int j = 0; j < 4; ++j) acc[i][j] = z4;

  // staging: call = 8 phys rows (1KB). lane L -> phys row +L>>3, phys unit
  // p = L&7 which holds logical {sub = p>>2, j = (p&3)^(r&3)}.
  const int slr = lane >> 3;
  const int sp = lane & 7;
  const int ssub = sp >> 2;

  auto stage = [&](int b, int k0) {
#pragma unroll
    for (int c = 0; c < 2; ++c) {
      const int r = wid * 16 + c * 8 + slr;
      const int jj = (sp & 3) ^ (r & 3);
      gld_lds16(Xb + (size_t)(m0 + 2 * r + ssub) * 1024 + k0 + jj * 8,
                As[b] + (wid * 16 + c * 8) * 64);
      gld_lds16(Wt + (size_t)(n0 + 2 * r + ssub) * 1024 + k0 + jj * 8,
                Bs[b] + (wid * 16 + c * 8) * 64);
    }
  };

  stage(0, 0);

  for (int i = 0; i < 32; ++i) {
    __syncthreads();                 // drains prefetch(i); frees buf (i-1)&1
    if (i < 31) stage((i + 1) & 1, (i + 1) * 32);

    const u16* __restrict__ Ab = As[i & 1];
    const u16* __restrict__ Bb = Bs[i & 1];
    bf16x8 af[4], bfr[4];
#pragma unroll
    for (int ii = 0; ii < 4; ++ii) {
      const int m = wm + ii * 16 + l16;
      const int r = m >> 1;
      af[ii] = *(const bf16x8*)(Ab + r * 64 + (m & 1) * 32 +
                                ((quad ^ (r & 3)) * 8));
    }
#pragma unroll
    for (int j = 0; j < 4; ++j) {
      const int nn = wn + j * 16 + l16;
      const int r = nn >> 1;
      bfr[j] = *(const bf16x8*)(Bb + r * 64 + (nn & 1) * 32 +
                                ((quad ^ (r & 3)) * 8));
    }
#pragma unroll
    for (int ii = 0; ii < 4; ++ii)
#pragma unroll
      for (int j = 0; j < 4; ++j)
        acc[ii][j] = MFMA16(af[ii], bfr[j], acc[ii][j]);
  }

  // epilogue (R2/R5-proven). C/D layout: col = l16 (n), row = quad*4+reg (m).
  const int b = m0 >> 10;
  const int h = n0 >> 7;
  const int sbase = (m0 & 1023) + wm;
  float bv4[4];
#pragma unroll
  for (int j = 0; j < 4; ++j) bv4[j] = bias[n0 + wn + j * 16 + l16];

  if (mat < 2) {
    u16* outp = (mat == 0 ? Qh : Kh) + (size_t)(b * 8 + h) * 1024 * 128;
#pragma unroll
    for (int i = 0; i < 4; ++i)
#pragma unroll
      for (int j = 0; j < 4; ++j) {
        const int d = wn + j * 16 + l16;
#pragma unroll
        for (int r = 0; r < 4; ++r) {
          const int s = sbase + i * 16 + quad * 4 + r;
          outp[(size_t)s * 128 + d] = f2b(acc[i][j][r] + bv4[j]);
        }
      }
  } else {
    // V^T: out[((b*8+h)*128 + d)*1024 + s]; 4 regs = 4 consecutive s.
    u16* outp = Vt + (size_t)(b * 8 + h) * 128 * 1024;
#pragma unroll
    for (int i = 0; i < 4; ++i)
#pragma unroll
      for (int j = 0; j < 4; ++j) {
        const int d = wn + j * 16 + l16;
        const int s = sbase + i * 16 + quad * 4;
        ushort4 pk;
        pk.x = f2b(acc[i][j][0] + bv4[j]);
        pk.y = f2b(acc[i][j][1] + bv4[j]);
        pk.z = f2b(acc[i][j][2] + bv4[j]);
        pk.w = f2b(acc[i][j][3] + bv4[j]);
        *(ushort4*)(outp + (size_t)d * 1024 + s) = pk;
      }
  }
}

// ---------------------------------------------------------------------------
// Kernel 3: attention. grid 1024 (64 bh x 16 qtiles of 64), block 256
// (4 waves x 16 q-rows). BK=32, Ks+Vs double-buffered, single barrier/iter.
// Vs and Ps pair-interleaved into 128B rows -> PV-side LDS reads uniform
// (were 8-way conflicted in R4). S^T = MFMA(kf,qf); O^T = MFMA(vf,pa).
// 36KB LDS -> 4 blocks/CU = 16 waves/CU. LPT + XCD swizzle.
// ---------------------------------------------------------------------------
__global__ __launch_bounds__(256, 4) void attn_kernel(const u16* __restrict__ Qh,
                                                      const u16* __restrict__ Kh,
                                                      const u16* __restrict__ Vt,
                                                      float* __restrict__ out) {
  const int id = blockIdx.x;
  const int bh = (id & 7) * 8 + ((id >> 3) & 7);   // XCD x owns 8 heads
  const int qt = 15 - (id >> 6);                   // heavy tiles first (LPT)
  const int q0 = qt * 64;

  const int tid = threadIdx.x;
  const int wid = tid >> 6;
  const int lane = tid & 63;
  const int quad = lane >> 4;
  const int l16 = lane & 15;

  __shared__ u16 Ks[2][32 * 128];   // [key][d] 256B rows, xor16 units, 8KB ea
  __shared__ u16 Vs[2][64 * 64];    // d-pair rows: 64 x 128B, 8KB ea
  __shared__ u16 Ps[4][8 * 64];     // per-wave q-pair rows: 8 x 128B, 1KB

  const u16* __restrict__ Qbase = Qh + (size_t)bh * 1024 * 128;
  const u16* __restrict__ Kbase = Kh + (size_t)bh * 1024 * 128;
  const u16* __restrict__ Vbase = Vt + (size_t)bh * 128 * 1024;

  const int qw = q0 + wid * 16;     // this wave's 16 q-rows
  const int qrow = qw + l16;

  // Q B-frags (for S^T = MFMA(kf,qf)): lane l16 = q, k = quad*8+j.
  bf16x8 qf[4];
#pragma unroll
  for (int c = 0; c < 4; ++c)
    qf[c] = *(const bf16x8*)(Qbase + (size_t)qrow * 128 + c * 32 + quad * 8);

  const floatx4 z4 = {0.f, 0.f, 0.f, 0.f};
  floatx4 o[8];
#pragma unroll
  for (int dt = 0; dt < 8; ++dt) o[dt] = z4;
  float lacc = 0.f;

  // staging lane pieces
  const int slr = lane >> 3;        // V: phys row within call
  const int sp = lane & 7;
  const int ssub = sp >> 2;

  auto stage = [&](int b, int k0) {
    // K: 32 rows x 256B; wave stages 8 rows, 4 rows (1KB)/call, xor16.
#pragma unroll
    for (int c = 0; c < 2; ++c) {
      const int r0 = wid * 8 + c * 4;
      const int row = r0 + quad;
      gld_lds16(Kbase + (size_t)(k0 + row) * 128 + ((l16 ^ (row & 15)) * 8),
                Ks[b] + r0 * 128);
    }
    // V: 64 phys rows (d-pairs) x 128B; wave stages 16 rows, 8 rows/call.
#pragma unroll
    for (int c = 0; c < 2; ++c) {
      const int r = wid * 16 + c * 8 + slr;
      const int jj = (sp & 3) ^ (r & 3);
      gld_lds16(Vbase + (size_t)(2 * r + ssub) * 1024 + k0 + jj * 8,
                Vs[b] + (wid * 16 + c * 8) * 64);
    }
  };

  const int n = (q0 + 64) >> 5;     // 32-key iterations: 2..32
  stage(0, 0);

  for (int i = 0; i < n; ++i) {
    const int k0 = i << 5;
    __syncthreads();                // drains prefetch(i); frees buf (i-1)&1
    if (i + 1 < n) stage((i + 1) & 1, k0 + 32);

    if (k0 < qw + 16) {             // wave-uniform causal live check
      const u16* __restrict__ Kb = Ks[i & 1];
      const u16* __restrict__ Vb = Vs[i & 1];

      // QK: two 16-key S^T tiles; pack P into pair-interleaved Ps.
#pragma unroll
      for (int f = 0; f < 2; ++f) {
        bf16x8 kf[4];
#pragma unroll
        for (int c = 0; c < 4; ++c)
          kf[c] = *(const bf16x8*)(Kb + (f * 16 + l16) * 128 +
                                   (((c * 4 + quad) ^ l16) * 8));
        floatx4 st = z4;
#pragma unroll
        for (int c = 0; c < 4; ++c) st = MFMA16(kf[c], qf[c], st);
        const int kb = k0 + f * 16 + quad * 4;
        float p[4];
#pragma unroll
        for (int r = 0; r < 4; ++r) {
          const float e = fminf(__expf(st[r] * RSCALE), 85.f);
          p[r] = (kb + r > qrow) ? 0.f : __expf(e);
        }
        lacc += (p[0] + p[1]) + (p[2] + p[3]);
        uint2 pk;
        pk.x = (u32)f2b(p[0]) | ((u32)f2b(p[1]) << 16);
        pk.y = (u32)f2b(p[2]) | ((u32)f2b(p[3]) << 16);
        // q = l16 -> phys row l16>>1, half (l16&1)*64B; 8B slot s8 = f*4+quad,
        // 16B unit s8>>1 xor-swizzled by (row&3).
        const int prow = l16 >> 1;
        const int s8 = f * 4 + quad;
        *(uint2*)((char*)Ps[wid] + prow * 128 + (l16 & 1) * 64 +
                  (((s8 >> 1) ^ (prow & 3)) * 16) + (s8 & 1) * 8) = pk;
      }
      asm volatile("s_waitcnt lgkmcnt(0)" ::: "memory");  // own P visible

      // pa: B[k=key(quad*8+e)][n=q(l16)] from pair-interleaved Ps.
      const int prow = l16 >> 1;
      const bf16x8 pa = *(const bf16x8*)((char*)Ps[wid] + prow * 128 +
                                         (l16 & 1) * 64 +
                                         ((quad ^ (prow & 3)) * 16));
      // vf: A[m=d(l16 of dt*16+l16)][k=key] from pair-interleaved Vs.
#pragma unroll
      for (int dt = 0; dt < 8; ++dt) {
        const int d = dt * 16 + l16;
        const int vr = d >> 1;
        const bf16x8 vf = *(const bf16x8*)(Vb + vr * 64 + (d & 1) * 32 +
                                           ((quad ^ (vr & 3)) * 8));
        o[dt] = MFMA16(vf, pa, o[dt]);
      }
    }
  }

  // l reduce across quads (lanes sharing l16), normalize, store.
  float s = lacc;
  s += __shfl_xor(s, 16);
  s += __shfl_xor(s, 32);
  const float linv = 1.0f / s;

  // O^T C-layout: col(l16)=q, row(quad*4+r)=d -> contiguous float4.
  float* outp = out + (size_t)(bh >> 3) * 1024 * 1024 + (bh & 7) * 128;
#pragma unroll
  for (int dt = 0; dt < 8; ++dt) {
    float4 v;
    v.x = o[dt][0] * linv;
    v.y = o[dt][1] * linv;
    v.z = o[dt][2] * linv;
    v.w = o[dt][3] * linv;
    *(float4*)(outp + (size_t)qrow * 1024 + dt * 16 + quad * 4) = v;
  }
}

// ---------------------------------------------------------------------------
extern "C" void kernel_launch(void* const* d_in, const int* in_sizes, int n_in,
                              void* d_out, int out_size, void* d_ws,
                              size_t ws_size, hipStream_t stream) {
  const float* X = (const float*)d_in[0];
  const float* Wq = (const float*)d_in[1];
  const float* bq = (const float*)d_in[2];
  const float* Wk = (const float*)d_in[3];
  const float* bk = (const float*)d_in[4];
  const float* Wv = (const float*)d_in[5];
  const float* bv = (const float*)d_in[6];
  float* out = (float*)d_out;

  char* ws = (char*)d_ws;
  u16* Xb  = (u16*)(ws);                         // 16 MB  bf16 X
  u16* Wtb = (u16*)(ws + (16u << 20));           //  6 MB  bf16 W^T x3
  u16* Qh  = (u16*)(ws + (22u << 20));           // 16 MB  [B,H,S,DH]
  u16* Kh  = (u16*)(ws + (38u << 20));           // 16 MB  [B,H,S,DH]
  u16* Vt  = (u16*)(ws + (54u << 20));           // 16 MB  [B,H,DH,S]

  prep_kernel<<<8192 + 3072, 256, 0, stream>>>((const float4*)X, Xb, Wq, Wk,
                                               Wv, Wtb);
  dim3 gg(64, 8, 3);
  gemm_qkv_kernel<<<gg, 256, 0, stream>>>(Xb, Wtb, bq, bk, bv, Qh, Kh, Vt);
  attn_kernel<<<1024, 256, 0, stream>>>(Qh, Kh, Vt, out);
}